// Round 2
// baseline (220.518 us; speedup 1.0000x reference)
//
#include <hip/hip_runtime.h>

// Problem constants (fixed-shape problem)
#define BB 4
#define CC 16
#define KK 16
#define HWP (512 * 512)
#define TILE 512
#define NTILES (HWP / TILE)       // 512 tiles per batch
#define THREADS 256
#define JITERS (TILE / 64)        // 8: each iter, 16 lanes x 4 px = 64 pixels

__device__ __forceinline__ float fmaxf_(float a, float b) { return a > b ? a : b; }

__global__ __launch_bounds__(THREADS, 8) void disc_partial_kernel(
    const float* __restrict__ emb, const int* __restrict__ masks,
    float* __restrict__ ws_cnt, float* __restrict__ ws_sum, float* __restrict__ ws_sq)
{
    __shared__ unsigned short bits[TILE];   // per-pixel 16-bit mask field
    __shared__ int wcnt[4][KK];             // per-wave per-k fg counts

    const int tid = threadIdx.x;
    const int b = blockIdx.x / NTILES;
    const int tile = blockIdx.x % NTILES;
    const size_t tile0 = (size_t)tile * TILE;

    // ---- phase 1: pack 16 mask planes into per-pixel bitmask in LDS ----
    // thread t owns pixels 2t, 2t+1; int2 loads are 8B/lane, coalesced per plane
    const int2* mbase2 = (const int2*)(masks + (size_t)b * KK * HWP + tile0);
    unsigned v0 = 0, v1 = 0;
    #pragma unroll
    for (int k = 0; k < KK; ++k) {
        int2 mm = mbase2[(size_t)k * (HWP / 2) + tid];
        v0 |= (mm.x > 0 ? 1u : 0u) << k;
        v1 |= (mm.y > 0 ? 1u : 0u) << k;
    }
    ((unsigned*)bits)[tid] = v0 | (v1 << 16);   // little-endian: bits[2t]=v0, bits[2t+1]=v1

    // counts via ballot (keeps the count FMA out of the phase-2 inner loop)
    const int lane = tid & 63;
    const int wave = tid >> 6;
    int mycnt = 0;
    #pragma unroll
    for (int k = 0; k < KK; ++k) {
        unsigned long long b0 = __ballot((v0 >> k) & 1u);
        unsigned long long b1 = __ballot((v1 >> k) & 1u);
        if (lane == k) mycnt = __popcll(b0) + __popcll(b1);
    }
    if (lane < KK) wcnt[wave][lane] = mycnt;
    __syncthreads();

    // ---- phase 2: 16-thread group per channel; 4 px/lane/iter (float4) ----
    const int c = tid >> 4;
    const int l = tid & 15;
    const float4* e4 = (const float4*)(emb + ((size_t)b * CC + c) * HWP + tile0);
    const ushort4* b4 = (const ushort4*)bits;

    float s[KK], q[KK];
    #pragma unroll
    for (int k = 0; k < KK; ++k) { s[k] = 0.f; q[k] = 0.f; }

    #pragma unroll
    for (int j = 0; j < JITERS; ++j) {
        float4 e = e4[j * 16 + l];
        ushort4 vv = b4[j * 16 + l];
        const float ex[4] = {e.x, e.y, e.z, e.w};
        const unsigned vx[4] = {vv.x, vv.y, vv.z, vv.w};
        #pragma unroll
        for (int p = 0; p < 4; ++p) {
            float ev = ex[p];
            float ev2 = ev * ev;
            unsigned v = vx[p];
            #pragma unroll
            for (int k = 0; k < KK; ++k) {
                float fm = (float)((v >> k) & 1u);
                s[k] = fmaf(fm, ev, s[k]);
                q[k] = fmaf(fm, ev2, q[k]);
            }
        }
    }

    // ---- butterfly reduce across the 16-lane group; lane l keeps k==l ----
    float out_s = 0.f, out_q = 0.f;
    #pragma unroll
    for (int k = 0; k < KK; ++k) {
        float ts = s[k], tq = q[k];
        #pragma unroll
        for (int d = 8; d >= 1; d >>= 1) {
            ts += __shfl_xor(ts, d, 64);
            tq += __shfl_xor(tq, d, 64);
        }
        if (l == k) { out_s = ts; out_q = tq; }
    }
    atomicAdd(&ws_sum[((size_t)b * KK + l) * CC + c], out_s);
    atomicAdd(&ws_sq [((size_t)b * KK + l) * CC + c], out_q);
    if (tid < KK) {
        float ctot = (float)(wcnt[0][tid] + wcnt[1][tid] + wcnt[2][tid] + wcnt[3][tid]);
        atomicAdd(&ws_cnt[b * KK + tid], ctot);
    }
}

__global__ __launch_bounds__(256) void disc_finalize_kernel(
    const float* __restrict__ ws_cnt, const float* __restrict__ ws_sum,
    const float* __restrict__ ws_sq, float* __restrict__ out)
{
    __shared__ float means[BB][KK][CC];
    __shared__ float partial[BB];
    const int tid = threadIdx.x;
    const int b = tid >> 6;       // one wave per batch
    const int lane = tid & 63;

    const float DELTA_PULL = 0.5f;
    const float DELTA_PUSH = 1.5f;
    const float EPS = 1e-6f;

    float cntk = 0.f;
    bool valid = false;
    float pull_k = 0.f;
    if (lane < KK) {
        int k = lane;
        cntk = ws_cnt[b * KK + k];
        valid = cntk > 0.f;
        float safe = fmaxf_(cntk, 1.f);
        float acc_sq = 0.f, acc_ss = 0.f;
        #pragma unroll
        for (int c = 0; c < CC; ++c) {
            float sv = ws_sum[(b * KK + k) * CC + c];
            means[b][k][c] = sv / safe;
            acc_sq += ws_sq[(b * KK + k) * CC + c];
            acc_ss += sv * sv;
        }
        if (valid) pull_k = (acc_sq - acc_ss / cntk) / (cntk + EPS);
    }

    unsigned long long bal = __ballot(lane < KK && valid);
    float M = (float)__popcll(bal);

    float ps = pull_k;
    #pragma unroll
    for (int d = 32; d >= 1; d >>= 1) ps += __shfl_xor(ps, d, 64);
    float pull_b = ps / fmaxf_(M, 1.f);

    __syncthreads();

    float push = 0.f;
    for (int t = lane; t < KK * KK; t += 64) {
        int i = t >> 4, j = t & 15;
        if (i < j && ((bal >> i) & 1ull) && ((bal >> j) & 1ull)) {
            float d2 = 1e-12f;
            #pragma unroll
            for (int c = 0; c < CC; ++c) {
                float df = means[b][i][c] - means[b][j][c];
                d2 = fmaf(df, df, d2);
            }
            float dist = sqrtf(d2);
            float h = fmaxf_(DELTA_PUSH - dist, 0.f);
            push += h * h;
        }
    }
    #pragma unroll
    for (int d = 32; d >= 1; d >>= 1) push += __shfl_xor(push, d, 64);

    if (lane == 0) {
        float npairs = M * (M - 1.f) * 0.5f;
        float push_b = (M > 1.f) ? push / fmaxf_(npairs, 1.f) : 0.f;
        partial[b] = DELTA_PULL * pull_b + push_b;
    }
    __syncthreads();
    if (tid == 0) {
        out[0] = (partial[0] + partial[1] + partial[2] + partial[3]) * 0.25f;
    }
}

extern "C" void kernel_launch(void* const* d_in, const int* in_sizes, int n_in,
                              void* d_out, int out_size, void* d_ws, size_t ws_size,
                              hipStream_t stream) {
    const float* emb = (const float*)d_in[0];
    const int* masks = (const int*)d_in[1];
    float* ws = (float*)d_ws;
    float* ws_cnt = ws;               // 64 floats
    float* ws_sum = ws + 64;          // 1024 floats
    float* ws_sq  = ws + 64 + 1024;   // 1024 floats

    hipMemsetAsync(d_ws, 0, (64 + 1024 + 1024) * sizeof(float), stream);

    dim3 grid(BB * NTILES);
    disc_partial_kernel<<<grid, THREADS, 0, stream>>>(emb, masks, ws_cnt, ws_sum, ws_sq);
    disc_finalize_kernel<<<1, 256, 0, stream>>>(ws_cnt, ws_sum, ws_sq, (float*)d_out);
}

// Round 3
// 166.088 us; speedup vs baseline: 1.3277x; 1.3277x over previous
//
#include <hip/hip_runtime.h>

// Problem constants (fixed-shape problem)
#define BB 4
#define CC 16
#define KK 16
#define HWP (512 * 512)
#define TILE 1024
#define NTILES (HWP / TILE)       // 256 tiles per batch -> 1024 blocks
#define THREADS 256
#define JITERS (TILE / 64)        // 16: each iter, 16 lanes x 4 px (float4)
#define NSLICE 8                  // atomic contention slices
#define WSTOT (64 + 1024 + 1024)  // floats per slice: cnt | sum | sq

typedef float f2 __attribute__((ext_vector_type(2)));

__device__ __forceinline__ float fmaxf_(float a, float b) { return a > b ? a : b; }

__device__ __forceinline__ f2 fma2(float m, f2 ee, f2 acc) {
#if __has_builtin(__builtin_elementwise_fma)
    f2 mm = {m, m};
    return __builtin_elementwise_fma(mm, ee, acc);   // -> v_pk_fma_f32
#else
    acc.x = fmaf(m, ee.x, acc.x);
    acc.y = fmaf(m, ee.y, acc.y);
    return acc;
#endif
}

__global__ __launch_bounds__(THREADS, 4) void disc_partial_kernel(
    const float* __restrict__ emb, const int* __restrict__ masks,
    float* __restrict__ ws)   // NSLICE slices of [cnt 64 | sum 1024 | sq 1024]
{
    __shared__ unsigned short bits[TILE];   // per-pixel 16-bit mask field
    __shared__ int wcnt[4][KK];             // per-wave per-k fg counts

    const int tid = threadIdx.x;
    const int b = blockIdx.x / NTILES;
    const int tile = blockIdx.x % NTILES;
    const size_t tile0 = (size_t)tile * TILE;
    float* slice = ws + (size_t)(blockIdx.x & (NSLICE - 1)) * WSTOT;

    // ---- phase 1: pack 16 mask planes into per-pixel bitmask in LDS ----
    // thread t owns pixels 4t..4t+3 via int4 loads (16B/lane, coalesced per plane)
    const int4* mbase4 = (const int4*)(masks + (size_t)b * KK * HWP + tile0);
    unsigned v0 = 0, v1 = 0, v2 = 0, v3 = 0;
    #pragma unroll
    for (int k = 0; k < KK; ++k) {
        int4 mm = mbase4[(size_t)k * (HWP / 4) + tid];
        v0 |= (mm.x > 0 ? 1u : 0u) << k;
        v1 |= (mm.y > 0 ? 1u : 0u) << k;
        v2 |= (mm.z > 0 ? 1u : 0u) << k;
        v3 |= (mm.w > 0 ? 1u : 0u) << k;
    }
    uint2 packed;
    packed.x = v0 | (v1 << 16);
    packed.y = v2 | (v3 << 16);
    ((uint2*)bits)[tid] = packed;   // bits[4t..4t+3] = v0,v1,v2,v3

    // exact fg counts via ballot (keeps count-FMAs out of the phase-2 loop)
    const int lane = tid & 63;
    const int wave = tid >> 6;
    int mycnt = 0;
    #pragma unroll
    for (int k = 0; k < KK; ++k) {
        unsigned long long b0 = __ballot((v0 >> k) & 1u);
        unsigned long long b1 = __ballot((v1 >> k) & 1u);
        unsigned long long b2 = __ballot((v2 >> k) & 1u);
        unsigned long long b3 = __ballot((v3 >> k) & 1u);
        if (lane == k) mycnt = __popcll(b0) + __popcll(b1) + __popcll(b2) + __popcll(b3);
    }
    if (lane < KK) wcnt[wave][lane] = mycnt;
    __syncthreads();

    // ---- phase 2: 16-thread group per channel; 4 px/lane/iter (float4) ----
    const int c = tid >> 4;
    const int l = tid & 15;
    const float4* e4 = (const float4*)(emb + ((size_t)b * CC + c) * HWP + tile0);
    const ushort4* b4 = (const ushort4*)bits;

    f2 acc[KK];   // (sum, sq) per k -> v_pk_fma_f32
    #pragma unroll
    for (int k = 0; k < KK; ++k) { acc[k].x = 0.f; acc[k].y = 0.f; }

    #pragma unroll 4
    for (int j = 0; j < JITERS; ++j) {
        float4 e = e4[j * 16 + l];
        ushort4 vv = b4[j * 16 + l];
        const float ex[4] = {e.x, e.y, e.z, e.w};
        const unsigned vx[4] = {vv.x, vv.y, vv.z, vv.w};
        #pragma unroll
        for (int p = 0; p < 4; ++p) {
            float ev = ex[p];
            f2 ee = {ev, ev * ev};
            unsigned v = vx[p];
            #pragma unroll
            for (int k = 0; k < KK; ++k) {
                float fm = (float)((v >> k) & 1u);
                acc[k] = fma2(fm, ee, acc[k]);
            }
        }
    }

    // ---- butterfly reduce across the 16-lane group; lane l keeps k==l ----
    float out_s = 0.f, out_q = 0.f;
    #pragma unroll
    for (int k = 0; k < KK; ++k) {
        float ts = acc[k].x, tq = acc[k].y;
        #pragma unroll
        for (int d = 8; d >= 1; d >>= 1) {
            ts += __shfl_xor(ts, d, 64);
            tq += __shfl_xor(tq, d, 64);
        }
        if (l == k) { out_s = ts; out_q = tq; }
    }
    atomicAdd(&slice[64 + ((size_t)b * KK + l) * CC + c], out_s);
    atomicAdd(&slice[64 + 1024 + ((size_t)b * KK + l) * CC + c], out_q);
    if (tid < KK) {
        float ctot = (float)(wcnt[0][tid] + wcnt[1][tid] + wcnt[2][tid] + wcnt[3][tid]);
        atomicAdd(&slice[b * KK + tid], ctot);
    }
}

__global__ __launch_bounds__(256) void disc_finalize_kernel(
    const float* __restrict__ ws, float* __restrict__ out)
{
    __shared__ float red[WSTOT];             // slice-reduced [cnt|sum|sq]
    __shared__ float means[BB][KK][CC];
    __shared__ float partial[BB];
    const int tid = threadIdx.x;

    // ---- pre-reduce the NSLICE atomic slices with all 256 threads ----
    for (int idx = tid; idx < WSTOT; idx += 256) {
        float t = 0.f;
        #pragma unroll
        for (int s = 0; s < NSLICE; ++s) t += ws[(size_t)s * WSTOT + idx];
        red[idx] = t;
    }
    __syncthreads();

    const float* red_cnt = red;
    const float* red_sum = red + 64;
    const float* red_sq  = red + 64 + 1024;

    const int b = tid >> 6;       // one wave per batch
    const int lane = tid & 63;

    const float DELTA_PULL = 0.5f;
    const float DELTA_PUSH = 1.5f;
    const float EPS = 1e-6f;

    float cntk = 0.f;
    bool valid = false;
    float pull_k = 0.f;
    if (lane < KK) {
        int k = lane;
        cntk = red_cnt[b * KK + k];
        valid = cntk > 0.f;
        float safe = fmaxf_(cntk, 1.f);
        float acc_sq = 0.f, acc_ss = 0.f;
        #pragma unroll
        for (int c = 0; c < CC; ++c) {
            float sv = red_sum[(b * KK + k) * CC + c];
            means[b][k][c] = sv / safe;
            acc_sq += red_sq[(b * KK + k) * CC + c];
            acc_ss += sv * sv;
        }
        if (valid) pull_k = (acc_sq - acc_ss / cntk) / (cntk + EPS);
    }

    unsigned long long bal = __ballot(lane < KK && valid);
    float M = (float)__popcll(bal);

    float ps = pull_k;
    #pragma unroll
    for (int d = 32; d >= 1; d >>= 1) ps += __shfl_xor(ps, d, 64);
    float pull_b = ps / fmaxf_(M, 1.f);

    __syncthreads();

    float push = 0.f;
    for (int t = lane; t < KK * KK; t += 64) {
        int i = t >> 4, j = t & 15;
        if (i < j && ((bal >> i) & 1ull) && ((bal >> j) & 1ull)) {
            float d2 = 1e-12f;
            #pragma unroll
            for (int c = 0; c < CC; ++c) {
                float df = means[b][i][c] - means[b][j][c];
                d2 = fmaf(df, df, d2);
            }
            float dist = sqrtf(d2);
            float h = fmaxf_(DELTA_PUSH - dist, 0.f);
            push += h * h;
        }
    }
    #pragma unroll
    for (int d = 32; d >= 1; d >>= 1) push += __shfl_xor(push, d, 64);

    if (lane == 0) {
        float npairs = M * (M - 1.f) * 0.5f;
        float push_b = (M > 1.f) ? push / fmaxf_(npairs, 1.f) : 0.f;
        partial[b] = DELTA_PULL * pull_b + push_b;
    }
    __syncthreads();
    if (tid == 0) {
        out[0] = (partial[0] + partial[1] + partial[2] + partial[3]) * 0.25f;
    }
}

extern "C" void kernel_launch(void* const* d_in, const int* in_sizes, int n_in,
                              void* d_out, int out_size, void* d_ws, size_t ws_size,
                              hipStream_t stream) {
    const float* emb = (const float*)d_in[0];
    const int* masks = (const int*)d_in[1];
    float* ws = (float*)d_ws;

    hipMemsetAsync(d_ws, 0, NSLICE * WSTOT * sizeof(float), stream);

    dim3 grid(BB * NTILES);
    disc_partial_kernel<<<grid, THREADS, 0, stream>>>(emb, masks, ws);
    disc_finalize_kernel<<<1, 256, 0, stream>>>(ws, (float*)d_out);
}